// Round 3
// baseline (22742.285 us; speedup 1.0000x reference)
//
#include <hip/hip_runtime.h>
#include <hip/hip_cooperative_groups.h>
#include <math.h>

namespace cg = cooperative_groups;

#define BATCH 512
#define TLEN  64
#define HD    512
#define H2    1024
#define H3    1536
#define HQ    51
#define CHUNK 4096
#define ARENA_BIT 64
#define GRID  512

struct Task { int b, el, er, jl, slot; };

struct Args {
    const float* inp; const int* length;
    const float* W1; const float* b1; const float* W2; const float* b2;
    const float* Wq1; const float* bq1; const float* Wq2; const float* bq2;
    float* out;
    float* W1T; float* W2T; float* Vif; float* X2; float* arena; float* comp;
    int* posval; int* cidx;
    Task* itasks; Task* rtA; Task* rtB;
    int* rtiA; int* rtiB;
    int* counters;
};

__device__ __forceinline__ float sigf(float x) { return 1.0f / (1.0f + expf(-x)); }

__device__ __forceinline__ const float* node_ptr(const float* __restrict__ inp,
                                                 const float* __restrict__ arena,
                                                 int b, int enc)
{
    const float* base = (enc & ARENA_BIT) ? arena : inp;
    return base + ((long)b * TLEN + (enc & (ARENA_BIT - 1))) * HD;
}

__device__ __forceinline__ double score_accum(const float* __restrict__ wr,
                                              const float* __restrict__ nh, double bias)
{
    double s0 = 0.0, s1 = 0.0, s2 = 0.0, s3 = 0.0;
    for (int k = 0; k < HD; k += 4) {
        s0 += (double)wr[k + 0] * (double)nh[k + 0];
        s1 += (double)wr[k + 1] * (double)nh[k + 1];
        s2 += (double)wr[k + 2] * (double)nh[k + 2];
        s3 += (double)wr[k + 3] * (double)nh[k + 3];
    }
    return bias + s0 + s1 + s2 + s3;
}

// ================= fused-kernel device phases (numerics identical to R2 kernels) =================

__device__ __forceinline__ void g1_tile(const Args& A, const Task* __restrict__ tasks, int taskbase, int count,
                                        int rtile, int ctile,
                                        float* __restrict__ sA, float* __restrict__ sB,
                                        const float** spL, const float** spR, int* stok)
{
    int tid = threadIdx.x;
    int m_base = taskbase + rtile * 64;
    if (tid < 64) {
        int mg = m_base + tid;
        if (mg < count) {
            Task t = tasks[mg];
            spL[tid] = node_ptr(A.inp, A.arena, t.b, t.el);
            spR[tid] = node_ptr(A.inp, A.arena, t.b, t.er);
            stok[tid] = 1;
        } else { spL[tid] = A.inp; spR[tid] = A.inp; stok[tid] = 0; }
    }
    __syncthreads();
    const int n0 = ctile * 64;
    const int ty = tid >> 4, tx = tid & 15;
    const int mrow = tid >> 2, mk = (tid & 3) * 8;
    const int wrow = tid >> 3, wn = (tid & 7) * 8;
    float acc[4][4] = {};
    for (int kt = 0; kt < 32; ++kt) {
        int k0 = kt * 32;
        {
            const float* src = (k0 < HD ? spL[mrow] : spR[mrow]) + (k0 < HD ? (k0 + mk) : (k0 + mk - HD));
            float4 v0 = *(const float4*)src;
            float4 v1 = *(const float4*)(src + 4);
            sA[(mk + 0) * 68 + mrow] = v0.x; sA[(mk + 1) * 68 + mrow] = v0.y;
            sA[(mk + 2) * 68 + mrow] = v0.z; sA[(mk + 3) * 68 + mrow] = v0.w;
            sA[(mk + 4) * 68 + mrow] = v1.x; sA[(mk + 5) * 68 + mrow] = v1.y;
            sA[(mk + 6) * 68 + mrow] = v1.z; sA[(mk + 7) * 68 + mrow] = v1.w;
        }
        {
            const float* src = &A.W1T[(long)(k0 + wrow) * H3 + n0 + wn];
            float4 v0 = *(const float4*)src;
            float4 v1 = *(const float4*)(src + 4);
            *(float4*)&sB[wrow * 64 + wn] = v0;
            *(float4*)&sB[wrow * 64 + wn + 4] = v1;
        }
        __syncthreads();
        #pragma unroll
        for (int kk = 0; kk < 32; ++kk) {
            float4 av = *(const float4*)&sA[kk * 68 + ty * 4];
            float4 wv = *(const float4*)&sB[kk * 64 + tx * 4];
            acc[0][0] += av.x * wv.x; acc[0][1] += av.x * wv.y; acc[0][2] += av.x * wv.z; acc[0][3] += av.x * wv.w;
            acc[1][0] += av.y * wv.x; acc[1][1] += av.y * wv.y; acc[1][2] += av.y * wv.z; acc[1][3] += av.y * wv.w;
            acc[2][0] += av.z * wv.x; acc[2][1] += av.z * wv.y; acc[2][2] += av.z * wv.z; acc[2][3] += av.z * wv.w;
            acc[3][0] += av.w * wv.x; acc[3][1] += av.w * wv.y; acc[3][2] += av.w * wv.z; acc[3][3] += av.w * wv.w;
        }
        __syncthreads();
    }
    #pragma unroll
    for (int mi = 0; mi < 4; ++mi) {
        int ml = ty * 4 + mi;
        if (stok[ml]) {
            int vrow = rtile * 64 + ml;
            int c = n0 + tx * 4;
            float4 v;
            v.x = acc[mi][0] + A.b1[c + 0];
            v.y = acc[mi][1] + A.b1[c + 1];
            v.z = acc[mi][2] + A.b1[c + 2];
            v.w = acc[mi][3] + A.b1[c + 3];
            if (n0 < H2) {
                *(float4*)&A.Vif[(long)vrow * H2 + c] = v;
            } else {
                int c2 = c - H2;
                float4 rs;
                rs.x = sigf(v.x); rs.y = sigf(v.y); rs.z = sigf(v.z); rs.w = sigf(v.w);
                float4 l = *(const float4*)(spL[ml] + c2);
                float4 r = *(const float4*)(spR[ml] + c2);
                float4 xl, xr;
                xl.x = l.x * rs.x; xl.y = l.y * rs.y; xl.z = l.z * rs.z; xl.w = l.w * rs.w;
                xr.x = r.x * rs.x; xr.y = r.y * rs.y; xr.z = r.z * rs.z; xr.w = r.w * rs.w;
                *(float4*)&A.X2[(long)vrow * H2 + c2] = xl;
                *(float4*)&A.X2[(long)vrow * H2 + HD + c2] = xr;
            }
        }
    }
    __syncthreads();
}

__device__ __forceinline__ void g2_tile(const Args& A, const Task* __restrict__ tasks, int taskbase, int count,
                                        int rtile, int ctile,
                                        float* __restrict__ sA, float* __restrict__ sB,
                                        const float** spL, const float** spR, int* sdr, int* stok)
{
    int tid = threadIdx.x;
    int m_base = taskbase + rtile * 64;
    if (tid < 64) {
        int mg = m_base + tid;
        if (mg < count) {
            Task t = tasks[mg];
            spL[tid] = node_ptr(A.inp, A.arena, t.b, t.el);
            spR[tid] = node_ptr(A.inp, A.arena, t.b, t.er);
            sdr[tid] = t.b * TLEN + t.slot;
            stok[tid] = 1;
        } else { spL[tid] = A.inp; spR[tid] = A.inp; sdr[tid] = 0; stok[tid] = 0; }
    }
    __syncthreads();
    const int n0 = ctile * 64;
    const int ty = tid >> 4, tx = tid & 15;
    const int mrow = tid >> 2, mk = (tid & 3) * 8;
    const int wrow = tid >> 3, wn = (tid & 7) * 8;
    float acc[4][4] = {};
    for (int kt = 0; kt < 32; ++kt) {
        int k0 = kt * 32;
        {
            const float* src = &A.X2[(long)(rtile * 64 + mrow) * H2 + k0 + mk];
            float4 v0 = *(const float4*)src;
            float4 v1 = *(const float4*)(src + 4);
            sA[(mk + 0) * 68 + mrow] = v0.x; sA[(mk + 1) * 68 + mrow] = v0.y;
            sA[(mk + 2) * 68 + mrow] = v0.z; sA[(mk + 3) * 68 + mrow] = v0.w;
            sA[(mk + 4) * 68 + mrow] = v1.x; sA[(mk + 5) * 68 + mrow] = v1.y;
            sA[(mk + 6) * 68 + mrow] = v1.z; sA[(mk + 7) * 68 + mrow] = v1.w;
        }
        {
            const float* src = &A.W2T[(long)(k0 + wrow) * HD + n0 + wn];
            float4 v0 = *(const float4*)src;
            float4 v1 = *(const float4*)(src + 4);
            *(float4*)&sB[wrow * 64 + wn] = v0;
            *(float4*)&sB[wrow * 64 + wn + 4] = v1;
        }
        __syncthreads();
        #pragma unroll
        for (int kk = 0; kk < 32; ++kk) {
            float4 av = *(const float4*)&sA[kk * 68 + ty * 4];
            float4 wv = *(const float4*)&sB[kk * 64 + tx * 4];
            acc[0][0] += av.x * wv.x; acc[0][1] += av.x * wv.y; acc[0][2] += av.x * wv.z; acc[0][3] += av.x * wv.w;
            acc[1][0] += av.y * wv.x; acc[1][1] += av.y * wv.y; acc[1][2] += av.y * wv.z; acc[1][3] += av.y * wv.w;
            acc[2][0] += av.z * wv.x; acc[2][1] += av.z * wv.y; acc[2][2] += av.z * wv.z; acc[2][3] += av.z * wv.w;
            acc[3][0] += av.w * wv.x; acc[3][1] += av.w * wv.y; acc[3][2] += av.w * wv.z; acc[3][3] += av.w * wv.w;
        }
        __syncthreads();
    }
    #pragma unroll
    for (int mi = 0; mi < 4; ++mi) {
        int ml = ty * 4 + mi;
        if (stok[ml]) {
            int vrow = rtile * 64 + ml;
            int c = n0 + tx * 4;
            float4 hh;
            hh.x = acc[mi][0] + A.b2[c + 0];
            hh.y = acc[mi][1] + A.b2[c + 1];
            hh.z = acc[mi][2] + A.b2[c + 2];
            hh.w = acc[mi][3] + A.b2[c + 3];
            float4 vi = *(const float4*)&A.Vif[(long)vrow * H2 + c];
            float4 vf = *(const float4*)&A.Vif[(long)vrow * H2 + HD + c];
            float4 l = *(const float4*)(spL[ml] + c);
            float4 r = *(const float4*)(spR[ml] + c);
            float4 nh;
            nh.x = (l.x + r.x) * sigf(vf.x) + tanhf(hh.x) * sigf(vi.x);
            nh.y = (l.y + r.y) * sigf(vf.y) + tanhf(hh.y) * sigf(vi.y);
            nh.z = (l.z + r.z) * sigf(vf.z) + tanhf(hh.z) * sigf(vi.z);
            nh.w = (l.w + r.w) * sigf(vf.w) + tanhf(hh.w) * sigf(vi.w);
            *(float4*)&A.arena[(long)sdr[ml] * HD + c] = nh;
        }
    }
    __syncthreads();
}

__device__ __forceinline__ void select_phase(const Args& A, int i, long off_i,
                                             const Task* __restrict__ rtc, Task* __restrict__ rtn,
                                             const int* __restrict__ ric, int* __restrict__ rin,
                                             int* rc_nxt,
                                             float* __restrict__ snh, double* __restrict__ spart, int* __restrict__ ssh)
{
    int b = blockIdx.x, tid = threadIdx.x;
    int len = A.length[b];
    if (i == 62) {
        if (tid == 0 && len == TLEN) A.posval[b * TLEN + 0] = ARENA_BIT | A.cidx[b * TLEN + 0];
        return;
    }
    int ti0 = ric[b * 2 + 0], ti1 = ric[b * 2 + 1];
    if (ti0 >= 0) {
        const float* src = &A.arena[((long)b * TLEN + rtc[ti0].slot) * HD];
        for (int c = tid; c < HD; c += 256) snh[c] = src[c];
    }
    if (ti1 >= 0) {
        const float* src = &A.arena[((long)b * TLEN + rtc[ti1].slot) * HD];
        for (int c = tid; c < HD; c += 256) snh[HD + c] = src[c];
    }
    __syncthreads();
    int w = tid >> 6, lane = tid & 63;
    double p = 0.0;
    if (w < 2 && lane < HQ) {
        int ti = (w == 0) ? ti0 : ti1;
        if (ti >= 0) {
            double aa = score_accum(&A.Wq1[(long)lane * HD], &snh[w * HD], (double)A.bq1[lane]);
            p = tanh(aa) * (double)A.Wq2[lane];
        }
    }
    spart[(tid < 128) ? tid : 128 + (tid & 127)] = p;   // waves 0,1 meaningful; others park harmlessly
    __syncthreads();
    if (tid == 0) {
        if (ti0 >= 0) {
            double s = 0.0;
            for (int r = 0; r < HQ; ++r) s += spart[r];
            s += (double)A.bq2[0];
            A.comp[b * TLEN + rtc[ti0].jl] = (float)s;
        }
        if (ti1 >= 0) {
            double s = 0.0;
            for (int r = 0; r < HQ; ++r) s += spart[64 + r];
            s += (double)A.bq2[0];
            A.comp[b * TLEN + rtc[ti1].jl] = (float)s;
        }
    }
    __syncthreads();
    int L1 = 63 - i;
    if (tid == 0) {
        float best = -INFINITY; int bj = 0;
        for (int j = 0; j < L1; ++j) {
            float v = (i + 1 + j < len) ? A.comp[b * TLEN + j] : -3.402823466e38f;
            if (v > best) { best = v; bj = j; }
        }
        ssh[0] = bj;
    }
    __syncthreads();
    int bj = ssh[0];
    if (tid < L1) A.out[off_i + (long)b * L1 + tid] = (tid == bj) ? 1.0f : 0.0f;
    bool active = (i + 1) < len;
    if (active) {
        int vcnt = len - i - 2;
        if (tid == 0) {
            ssh[1] = A.cidx[b * TLEN + bj];
            ssh[2] = (bj < vcnt) ? A.cidx[b * TLEN + bj + 1] : -1;
        }
        __syncthreads();
        int sM = ssh[1], sOld = ssh[2];
        int newL = 63 - i;
        int pv = 0;  bool dp = (tid >= bj + 1 && tid <= newL - 1);
        if (dp) pv = A.posval[b * TLEN + tid + 1];
        float cv = 0; int civ = 0; bool dc = (tid >= bj + 1 && tid <= newL - 2);
        if (dc) { cv = A.comp[b * TLEN + tid + 1]; civ = A.cidx[b * TLEN + tid + 1]; }
        __syncthreads();
        if (dp) A.posval[b * TLEN + tid] = pv;
        if (dc) { A.comp[b * TLEN + tid] = cv; A.cidx[b * TLEN + tid] = civ; }
        if (tid == 0) A.posval[b * TLEN + bj] = ARENA_BIT | sM;
        __syncthreads();
        if (tid == 0) {
            for (int t = 0; t < 2; ++t) {
                int jn = bj - 1 + t;
                int r = -1;
                if (jn >= 0 && jn < vcnt) {
                    int slot = (t == 0) ? A.cidx[b * TLEN + jn] : sOld;
                    A.cidx[b * TLEN + jn] = slot;
                    r = atomicAdd(rc_nxt, 1);
                    Task tk; tk.b = b;
                    tk.el = A.posval[b * TLEN + jn];
                    tk.er = A.posval[b * TLEN + jn + 1];
                    tk.jl = jn; tk.slot = slot;
                    rtn[r] = tk;
                }
                rin[b * 2 + t] = r;
            }
        }
    } else {
        if (tid == 0) { rin[b * 2] = -1; rin[b * 2 + 1] = -1; }
    }
}

__global__ void __launch_bounds__(256, 2) k_fused(Args A)
{
    cg::grid_group grid = cg::this_grid();
    __shared__ float sA[32 * 68];
    __shared__ float sB[32 * 64];
    __shared__ const float* spL[64];
    __shared__ const float* spR[64];
    __shared__ int sdr[64];
    __shared__ int stok[64];
    __shared__ float snh[4 * HD];
    __shared__ double spart[256];
    __shared__ int ssh[4];

    const int bid = blockIdx.x, tid = threadIdx.x;
    const long gtid = (long)bid * blockDim.x + tid;
    const long gnth = (long)gridDim.x * blockDim.x;

    // phase 0: prep
    for (long i = gtid; i < (long)H2 * H3; i += gnth) { long k = i / H3, r = i - k * H3; A.W1T[i] = A.W1[r * H2 + k]; }
    for (long i = gtid; i < (long)H2 * HD; i += gnth) { long k = i / HD, r = i - k * HD; A.W2T[i] = A.W2[r * H2 + k]; }
    for (long i = gtid; i < BATCH * TLEN; i += gnth) { int j = (int)(i % TLEN); A.posval[i] = j; A.cidx[i] = j; }
    for (long i = gtid; i < BATCH * 2; i += gnth) { A.rtiA[i] = -1; A.rtiB[i] = -1; }
    if (gtid < 8) A.counters[gtid] = 0;
    grid.sync();

    // phase 0b: init task build (block per batch)
    if (bid < BATCH) {
        int len = A.length[bid];
        for (int j = tid; j < len - 1; j += 256) {
            int idx = atomicAdd(&A.counters[0], 1);
            Task t; t.b = bid; t.el = j; t.er = j + 1; t.jl = j; t.slot = j;
            A.itasks[idx] = t;
        }
    }
    grid.sync();

    int icnt = *(volatile int*)&A.counters[0];

    // init chunks: G1 -> G2 -> G3
    for (int c = 0; c < 8; ++c) {
        int base = c * CHUNK;
        int rows = icnt - base; if (rows > CHUNK) rows = CHUNK;
        if (rows > 0) {
            int rtl = (rows + 63) >> 6;
            for (int t = bid; t < rtl * 24; t += gridDim.x)
                g1_tile(A, A.itasks, base, icnt, t % rtl, t / rtl, sA, sB, spL, spR, stok);
            grid.sync();
            for (int t = bid; t < rtl * 8; t += gridDim.x)
                g2_tile(A, A.itasks, base, icnt, t % rtl, t / rtl, sA, sB, spL, spR, sdr, stok);
            grid.sync();
            for (int t0 = bid * 4; t0 < rows; t0 += gridDim.x * 4) {
                int w = tid >> 6, lane = tid & 63;
                int tloc = t0 + w;
                bool ok = (tloc < rows);
                Task tk;
                if (ok) {
                    tk = A.itasks[base + tloc];
                    const float* src = &A.arena[((long)tk.b * TLEN + tk.slot) * HD];
                    for (int cc = lane; cc < HD; cc += 64) snh[w * HD + cc] = src[cc];
                }
                __syncthreads();
                double p = 0.0;
                if (ok && lane < HQ) {
                    double aa = score_accum(&A.Wq1[(long)lane * HD], &snh[w * HD], (double)A.bq1[lane]);
                    p = tanh(aa) * (double)A.Wq2[lane];
                }
                spart[w * 64 + lane] = p;
                __syncthreads();
                if (ok && lane == 0) {
                    double s = 0.0;
                    for (int r = 0; r < HQ; ++r) s += spart[w * 64 + r];
                    s += (double)A.bq2[0];
                    A.comp[tk.b * TLEN + tk.jl] = (float)s;
                }
                __syncthreads();
            }
            grid.sync();
        }
    }

    // main loop
    long off_i = (long)BATCH * HD;
    for (int i = 0; i < 63; ++i) {
        int par = i & 1;
        const Task* rtc = par ? A.rtB : A.rtA;
        Task* rtn = par ? A.rtA : A.rtB;
        const int* ric = par ? A.rtiB : A.rtiA;
        int* rin = par ? A.rtiA : A.rtiB;
        int* rc_nxt = &A.counters[1 + (par ^ 1)];
        if (bid == 0 && tid == 0) *rc_nxt = 0;
        int cnt = *(volatile int*)&A.counters[1 + par];
        int rtl = (cnt + 63) >> 6;
        for (int t = bid; t < rtl * 24; t += gridDim.x)
            g1_tile(A, rtc, 0, cnt, t % rtl, t / rtl, sA, sB, spL, spR, stok);
        grid.sync();
        for (int t = bid; t < rtl * 8; t += gridDim.x)
            g2_tile(A, rtc, 0, cnt, t % rtl, t / rtl, sA, sB, spL, spR, sdr, stok);
        grid.sync();
        if (bid < BATCH)
            select_phase(A, i, off_i, rtc, rtn, ric, rin, rc_nxt, snh, spart, ssh);
        if (i < 62) off_i += (long)BATCH * (63 - i);
        grid.sync();
    }

    // out: root per batch
    for (long idx = gtid; idx < (long)BATCH * HD; idx += gnth) {
        int b = (int)(idx / HD), c = (int)(idx % HD);
        const float* src = node_ptr(A.inp, A.arena, b, A.posval[b * TLEN]);
        A.out[idx] = src[c];
    }
}

// ===================== fallback: R2 multi-kernel path (proven) =====================

__global__ void k_prep(const float* __restrict__ W1, const float* __restrict__ W2,
                       float* __restrict__ W1T, float* __restrict__ W2T,
                       int* __restrict__ posval, int* __restrict__ cidx,
                       int* __restrict__ rti0, int* __restrict__ rti1,
                       int* __restrict__ counters)
{
    long tid = (long)blockIdx.x * blockDim.x + threadIdx.x;
    long nth = (long)gridDim.x * blockDim.x;
    for (long i = tid; i < (long)H2 * H3; i += nth) { long k = i / H3, r = i - k * H3; W1T[i] = W1[r * H2 + k]; }
    for (long i = tid; i < (long)H2 * HD; i += nth) { long k = i / HD, r = i - k * HD; W2T[i] = W2[r * H2 + k]; }
    for (long i = tid; i < BATCH * TLEN; i += nth) { int j = (int)(i % TLEN); posval[i] = j; cidx[i] = j; }
    for (long i = tid; i < BATCH * 2; i += nth) { rti0[i] = -1; rti1[i] = -1; }
    if (tid < 8) counters[tid] = 0;
}

__global__ void k_init_tasks(const int* __restrict__ length, Task* __restrict__ tasks, int* __restrict__ cnt)
{
    int b = blockIdx.x, j = threadIdx.x;
    int len = length[b];
    if (j < len - 1) {
        int idx = atomicAdd(cnt, 1);
        Task t; t.b = b; t.el = j; t.er = j + 1; t.jl = j; t.slot = j;
        tasks[idx] = t;
    }
}

__launch_bounds__(256, 2)
__global__ void k_g1(const Task* __restrict__ tasks, const int* __restrict__ cnt, int task_off,
                     const float* __restrict__ inp, const float* __restrict__ arena,
                     const float* __restrict__ W1T, const float* __restrict__ b1,
                     float* __restrict__ Vif, float* __restrict__ X2, int* zc)
{
    if (zc && blockIdx.x == 0 && blockIdx.y == 0 && threadIdx.x == 0) *zc = 0;
    __shared__ float XsT[32][68];
    __shared__ float Ws[32][64];
    __shared__ const float* pL[64];
    __shared__ const float* pR[64];
    __shared__ int tok[64];
    int count = *cnt;
    int m_base = task_off + blockIdx.x * 64;
    if (m_base >= count) return;
    int tid = threadIdx.x;
    if (tid < 64) {
        int mg = m_base + tid;
        if (mg < count) {
            Task t = tasks[mg];
            pL[tid] = node_ptr(inp, arena, t.b, t.el);
            pR[tid] = node_ptr(inp, arena, t.b, t.er);
            tok[tid] = 1;
        } else { pL[tid] = inp; pR[tid] = inp; tok[tid] = 0; }
    }
    __syncthreads();
    const int n0 = blockIdx.y * 64;
    const int ty = tid >> 4, tx = tid & 15;
    const int mrow = tid >> 2, mk = (tid & 3) * 8;
    const int wrow = tid >> 3, wn = (tid & 7) * 8;
    float acc[4][4] = {};
    for (int kt = 0; kt < 32; ++kt) {
        int k0 = kt * 32;
        {
            const float* src = (k0 < HD ? pL[mrow] : pR[mrow]) + (k0 < HD ? (k0 + mk) : (k0 + mk - HD));
            float4 v0 = *(const float4*)src;
            float4 v1 = *(const float4*)(src + 4);
            XsT[mk + 0][mrow] = v0.x; XsT[mk + 1][mrow] = v0.y;
            XsT[mk + 2][mrow] = v0.z; XsT[mk + 3][mrow] = v0.w;
            XsT[mk + 4][mrow] = v1.x; XsT[mk + 5][mrow] = v1.y;
            XsT[mk + 6][mrow] = v1.z; XsT[mk + 7][mrow] = v1.w;
        }
        {
            const float* src = &W1T[(long)(k0 + wrow) * H3 + n0 + wn];
            float4 v0 = *(const float4*)src;
            float4 v1 = *(const float4*)(src + 4);
            float* wd = &Ws[wrow][wn];
            *(float4*)wd = v0;
            *(float4*)(wd + 4) = v1;
        }
        __syncthreads();
        #pragma unroll
        for (int kk = 0; kk < 32; ++kk) {
            float4 av = *(const float4*)&XsT[kk][ty * 4];
            float4 wv = *(const float4*)&Ws[kk][tx * 4];
            acc[0][0] += av.x * wv.x; acc[0][1] += av.x * wv.y; acc[0][2] += av.x * wv.z; acc[0][3] += av.x * wv.w;
            acc[1][0] += av.y * wv.x; acc[1][1] += av.y * wv.y; acc[1][2] += av.y * wv.z; acc[1][3] += av.y * wv.w;
            acc[2][0] += av.z * wv.x; acc[2][1] += av.z * wv.y; acc[2][2] += av.z * wv.z; acc[2][3] += av.z * wv.w;
            acc[3][0] += av.w * wv.x; acc[3][1] += av.w * wv.y; acc[3][2] += av.w * wv.z; acc[3][3] += av.w * wv.w;
        }
        __syncthreads();
    }
    const int row0 = blockIdx.x * 64;
    #pragma unroll
    for (int mi = 0; mi < 4; ++mi) {
        int ml = ty * 4 + mi;
        if (!tok[ml]) continue;
        int row = row0 + ml;
        int c = n0 + tx * 4;
        float4 v;
        v.x = acc[mi][0] + b1[c + 0];
        v.y = acc[mi][1] + b1[c + 1];
        v.z = acc[mi][2] + b1[c + 2];
        v.w = acc[mi][3] + b1[c + 3];
        if (n0 < H2) {
            *(float4*)&Vif[(long)row * H2 + c] = v;
        } else {
            int c2 = c - H2;
            float4 rs;
            rs.x = sigf(v.x); rs.y = sigf(v.y); rs.z = sigf(v.z); rs.w = sigf(v.w);
            float4 l = *(const float4*)(pL[ml] + c2);
            float4 r = *(const float4*)(pR[ml] + c2);
            float4 xl, xr;
            xl.x = l.x * rs.x; xl.y = l.y * rs.y; xl.z = l.z * rs.z; xl.w = l.w * rs.w;
            xr.x = r.x * rs.x; xr.y = r.y * rs.y; xr.z = r.z * rs.z; xr.w = r.w * rs.w;
            *(float4*)&X2[(long)row * H2 + c2] = xl;
            *(float4*)&X2[(long)row * H2 + HD + c2] = xr;
        }
    }
}

__launch_bounds__(256, 2)
__global__ void k_g2(const Task* __restrict__ tasks, const int* __restrict__ cnt, int task_off,
                     const float* __restrict__ inp, float* __restrict__ arena,
                     const float* __restrict__ X2, const float* __restrict__ Vif,
                     const float* __restrict__ W2T, const float* __restrict__ b2)
{
    __shared__ float XsT[32][68];
    __shared__ float Ws[32][64];
    __shared__ const float* pL[64];
    __shared__ const float* pR[64];
    __shared__ int dr[64];
    __shared__ int tok[64];
    int count = *cnt;
    int m_base = task_off + blockIdx.x * 64;
    if (m_base >= count) return;
    int tid = threadIdx.x;
    if (tid < 64) {
        int mg = m_base + tid;
        if (mg < count) {
            Task t = tasks[mg];
            pL[tid] = node_ptr(inp, arena, t.b, t.el);
            pR[tid] = node_ptr(inp, arena, t.b, t.er);
            dr[tid] = t.b * TLEN + t.slot;
            tok[tid] = 1;
        } else { pL[tid] = inp; pR[tid] = inp; dr[tid] = 0; tok[tid] = 0; }
    }
    __syncthreads();
    const int n0 = blockIdx.y * 64;
    const int ty = tid >> 4, tx = tid & 15;
    const int mrow = tid >> 2, mk = (tid & 3) * 8;
    const int wrow = tid >> 3, wn = (tid & 7) * 8;
    const int row0 = blockIdx.x * 64;
    float acc[4][4] = {};
    for (int kt = 0; kt < 32; ++kt) {
        int k0 = kt * 32;
        {
            const float* src = &X2[(long)(row0 + mrow) * H2 + k0 + mk];
            float4 v0 = *(const float4*)src;
            float4 v1 = *(const float4*)(src + 4);
            XsT[mk + 0][mrow] = v0.x; XsT[mk + 1][mrow] = v0.y;
            XsT[mk + 2][mrow] = v0.z; XsT[mk + 3][mrow] = v0.w;
            XsT[mk + 4][mrow] = v1.x; XsT[mk + 5][mrow] = v1.y;
            XsT[mk + 6][mrow] = v1.z; XsT[mk + 7][mrow] = v1.w;
        }
        {
            const float* src = &W2T[(long)(k0 + wrow) * HD + n0 + wn];
            float4 v0 = *(const float4*)src;
            float4 v1 = *(const float4*)(src + 4);
            float* wd = &Ws[wrow][wn];
            *(float4*)wd = v0;
            *(float4*)(wd + 4) = v1;
        }
        __syncthreads();
        #pragma unroll
        for (int kk = 0; kk < 32; ++kk) {
            float4 av = *(const float4*)&XsT[kk][ty * 4];
            float4 wv = *(const float4*)&Ws[kk][tx * 4];
            acc[0][0] += av.x * wv.x; acc[0][1] += av.x * wv.y; acc[0][2] += av.x * wv.z; acc[0][3] += av.x * wv.w;
            acc[1][0] += av.y * wv.x; acc[1][1] += av.y * wv.y; acc[1][2] += av.y * wv.z; acc[1][3] += av.y * wv.w;
            acc[2][0] += av.z * wv.x; acc[2][1] += av.z * wv.y; acc[2][2] += av.z * wv.z; acc[2][3] += av.z * wv.w;
            acc[3][0] += av.w * wv.x; acc[3][1] += av.w * wv.y; acc[3][2] += av.w * wv.z; acc[3][3] += av.w * wv.w;
        }
        __syncthreads();
    }
    #pragma unroll
    for (int mi = 0; mi < 4; ++mi) {
        int ml = ty * 4 + mi;
        if (!tok[ml]) continue;
        int row = row0 + ml;
        int c = n0 + tx * 4;
        float4 hh;
        hh.x = acc[mi][0] + b2[c + 0];
        hh.y = acc[mi][1] + b2[c + 1];
        hh.z = acc[mi][2] + b2[c + 2];
        hh.w = acc[mi][3] + b2[c + 3];
        float4 vi = *(const float4*)&Vif[(long)row * H2 + c];
        float4 vf = *(const float4*)&Vif[(long)row * H2 + HD + c];
        float4 l = *(const float4*)(pL[ml] + c);
        float4 r = *(const float4*)(pR[ml] + c);
        float4 nh;
        nh.x = (l.x + r.x) * sigf(vf.x) + tanhf(hh.x) * sigf(vi.x);
        nh.y = (l.y + r.y) * sigf(vf.y) + tanhf(hh.y) * sigf(vi.y);
        nh.z = (l.z + r.z) * sigf(vf.z) + tanhf(hh.z) * sigf(vi.z);
        nh.w = (l.w + r.w) * sigf(vf.w) + tanhf(hh.w) * sigf(vi.w);
        *(float4*)&arena[(long)dr[ml] * HD + c] = nh;
    }
}

__launch_bounds__(64)
__global__ void k_g3(const Task* __restrict__ tasks, const int* __restrict__ cnt, int task_off,
                     const float* __restrict__ arena,
                     const float* __restrict__ Wq1, const float* __restrict__ bq1,
                     const float* __restrict__ Wq2, const float* __restrict__ bq2,
                     float* __restrict__ comp)
{
    int tgl = task_off + blockIdx.x;
    if (tgl >= *cnt) return;
    Task t = tasks[tgl];
    int tid = threadIdx.x;
    __shared__ float nh[HD];
    __shared__ double part[64];
    const float* src = &arena[((long)t.b * TLEN + t.slot) * HD];
    for (int c = tid; c < HD; c += 64) nh[c] = src[c];
    __syncthreads();
    double p = 0.0;
    if (tid < HQ) {
        double a = score_accum(&Wq1[(long)tid * HD], nh, (double)bq1[tid]);
        p = tanh(a) * (double)Wq2[tid];
    }
    part[tid] = p;
    __syncthreads();
    if (tid == 0) {
        double s = 0.0;
        for (int r = 0; r < HQ; ++r) s += part[r];
        s += (double)bq2[0];
        comp[t.b * TLEN + t.jl] = (float)s;
    }
}

__launch_bounds__(64)
__global__ void k_select(int iter, long off_i, const int* __restrict__ length,
                         float* __restrict__ comp, int* __restrict__ posval, int* __restrict__ cidx,
                         const int* __restrict__ rti_cur, int* __restrict__ rti_next,
                         const Task* __restrict__ rtasks_cur, Task* __restrict__ rtasks_next, int* __restrict__ rcnt_next,
                         const float* __restrict__ arena,
                         const float* __restrict__ Wq1, const float* __restrict__ bq1,
                         const float* __restrict__ Wq2, const float* __restrict__ bq2,
                         float* __restrict__ out, int final_flag)
{
    int b = blockIdx.x, tid = threadIdx.x;
    __shared__ float nh[HD];
    __shared__ double part[64];
    __shared__ int sh[4];
    int len = length[b];
    if (final_flag) {
        if (tid == 0 && len == TLEN) posval[b * TLEN + 0] = ARENA_BIT | cidx[b * TLEN + 0];
        return;
    }
    for (int t = 0; t < 2; ++t) {
        int ti = rti_cur[b * 2 + t];
        if (ti < 0) continue;
        Task tk = rtasks_cur[ti];
        const float* src = &arena[((long)b * TLEN + tk.slot) * HD];
        for (int c = tid; c < HD; c += 64) nh[c] = src[c];
        __syncthreads();
        double p = 0.0;
        if (tid < HQ) {
            double a = score_accum(&Wq1[(long)tid * HD], nh, (double)bq1[tid]);
            p = tanh(a) * (double)Wq2[tid];
        }
        part[tid] = p;
        __syncthreads();
        if (tid == 0) {
            double s = 0.0;
            for (int r = 0; r < HQ; ++r) s += part[r];
            s += (double)bq2[0];
            comp[b * TLEN + tk.jl] = (float)s;
        }
        __syncthreads();
    }
    int L1 = 63 - iter;
    if (tid == 0) {
        float best = -INFINITY; int bj = 0;
        for (int j = 0; j < L1; ++j) {
            float v = (iter + 1 + j < len) ? comp[b * TLEN + j] : -3.402823466e38f;
            if (v > best) { best = v; bj = j; }
        }
        sh[0] = bj;
    }
    __syncthreads();
    int bj = sh[0];
    for (int j = tid; j < L1; j += 64) out[off_i + (long)b * L1 + j] = (j == bj) ? 1.0f : 0.0f;
    bool active = (iter + 1) < len;
    if (active) {
        int vcnt = len - iter - 2;
        if (tid == 0) {
            sh[1] = cidx[b * TLEN + bj];
            sh[2] = (bj < vcnt) ? cidx[b * TLEN + bj + 1] : -1;
        }
        __syncthreads();
        int sM = sh[1], sOld = sh[2];
        int newL = 63 - iter;
        int pv = 0;  bool dp = (tid >= bj + 1 && tid <= newL - 1);
        if (dp) pv = posval[b * TLEN + tid + 1];
        float cv = 0; int civ = 0; bool dc = (tid >= bj + 1 && tid <= newL - 2);
        if (dc) { cv = comp[b * TLEN + tid + 1]; civ = cidx[b * TLEN + tid + 1]; }
        __syncthreads();
        if (dp) posval[b * TLEN + tid] = pv;
        if (dc) { comp[b * TLEN + tid] = cv; cidx[b * TLEN + tid] = civ; }
        if (tid == 0) posval[b * TLEN + bj] = ARENA_BIT | sM;
        __syncthreads();
        if (tid == 0) {
            for (int t = 0; t < 2; ++t) {
                int jn = bj - 1 + t;
                int r = -1;
                if (jn >= 0 && jn < vcnt) {
                    int slot = (t == 0) ? cidx[b * TLEN + jn] : sOld;
                    cidx[b * TLEN + jn] = slot;
                    r = atomicAdd(rcnt_next, 1);
                    Task tk; tk.b = b;
                    tk.el = posval[b * TLEN + jn];
                    tk.er = posval[b * TLEN + jn + 1];
                    tk.jl = jn; tk.slot = slot;
                    rtasks_next[r] = tk;
                }
                rti_next[b * 2 + t] = r;
            }
        }
    } else {
        if (tid == 0) { rti_next[b * 2] = -1; rti_next[b * 2 + 1] = -1; }
    }
}

__global__ void k_out(const int* __restrict__ posval, const float* __restrict__ inp,
                      const float* __restrict__ arena, float* __restrict__ out)
{
    int i = blockIdx.x * blockDim.x + threadIdx.x;
    if (i < BATCH * HD) {
        int b = i / HD, c = i % HD;
        const float* src = node_ptr(inp, arena, b, posval[b * TLEN + 0]);
        out[i] = src[c];
    }
}

// ===================== launch =====================

extern "C" void kernel_launch(void* const* d_in, const int* in_sizes, int n_in,
                              void* d_out, int out_size, void* d_ws, size_t ws_size,
                              hipStream_t stream)
{
    const float* inp = (const float*)d_in[0];
    const int* length = (const int*)d_in[1];
    const float* W1 = (const float*)d_in[2];
    const float* b1 = (const float*)d_in[3];
    const float* W2 = (const float*)d_in[4];
    const float* b2 = (const float*)d_in[5];
    const float* Wq1 = (const float*)d_in[6];
    const float* bq1 = (const float*)d_in[7];
    const float* Wq2 = (const float*)d_in[8];
    const float* bq2 = (const float*)d_in[9];
    float* out = (float*)d_out;

    char* p = (char*)d_ws;
    auto alloc = [&](size_t bytes) { char* r = p; p += (bytes + 255) & ~(size_t)255; return r; };
    float* W1T    = (float*)alloc((size_t)H2 * H3 * 4);
    float* W2T    = (float*)alloc((size_t)H2 * HD * 4);
    float* Vif    = (float*)alloc((size_t)CHUNK * H2 * 4);
    float* X2     = (float*)alloc((size_t)CHUNK * H2 * 4);
    float* arena  = (float*)alloc((size_t)BATCH * TLEN * HD * 4);
    float* comp   = (float*)alloc((size_t)BATCH * TLEN * 4);
    int*   posval = (int*)alloc((size_t)BATCH * TLEN * 4);
    int*   cidx   = (int*)alloc((size_t)BATCH * TLEN * 4);
    Task*  itasks  = (Task*)alloc((size_t)BATCH * (TLEN - 1) * sizeof(Task));
    Task*  rtasks0 = (Task*)alloc((size_t)2 * BATCH * sizeof(Task));
    Task*  rtasks1 = (Task*)alloc((size_t)2 * BATCH * sizeof(Task));
    int*   rti0 = (int*)alloc(BATCH * 2 * 4);
    int*   rti1 = (int*)alloc(BATCH * 2 * 4);
    int*   counters = (int*)alloc(256);
    int* cnt_init = counters + 0;
    int* rcnt0 = counters + 1;
    int* rcnt1 = counters + 2;

    Args a;
    a.inp = inp; a.length = length;
    a.W1 = W1; a.b1 = b1; a.W2 = W2; a.b2 = b2;
    a.Wq1 = Wq1; a.bq1 = bq1; a.Wq2 = Wq2; a.bq2 = bq2;
    a.out = out;
    a.W1T = W1T; a.W2T = W2T; a.Vif = Vif; a.X2 = X2; a.arena = arena; a.comp = comp;
    a.posval = posval; a.cidx = cidx;
    a.itasks = itasks; a.rtA = rtasks0; a.rtB = rtasks1;
    a.rtiA = rti0; a.rtiB = rti1;
    a.counters = counters;

    void* kp[] = { (void*)&a };
    hipError_t err = hipLaunchCooperativeKernel((const void*)k_fused, dim3(GRID), dim3(256), kp, 0, stream);
    if (err == hipSuccess) return;
    (void)hipGetLastError();   // clear error state; fall back to multi-kernel path

    k_prep<<<2048, 256, 0, stream>>>(W1, W2, W1T, W2T, posval, cidx, rti0, rti1, counters);
    k_init_tasks<<<BATCH, 64, 0, stream>>>(length, itasks, cnt_init);
    for (int c = 0; c < 8; ++c) {
        k_g1<<<dim3(CHUNK / 64, 24), 256, 0, stream>>>(itasks, cnt_init, c * CHUNK, inp, arena, W1T, b1, Vif, X2, nullptr);
        k_g2<<<dim3(CHUNK / 64, 8), 256, 0, stream>>>(itasks, cnt_init, c * CHUNK, inp, arena, X2, Vif, W2T, b2);
        k_g3<<<CHUNK, 64, 0, stream>>>(itasks, cnt_init, c * CHUNK, arena, Wq1, bq1, Wq2, bq2, comp);
    }
    long offi = (long)BATCH * HD;
    for (int i = 0; i < 63; ++i) {
        int par = i & 1;
        Task* rt_cur = par ? rtasks1 : rtasks0;
        Task* rt_nxt = par ? rtasks0 : rtasks1;
        int* rc_cur = par ? rcnt1 : rcnt0;
        int* rc_nxt = par ? rcnt0 : rcnt1;
        int* ri_cur = par ? rti1 : rti0;
        int* ri_nxt = par ? rti0 : rti1;
        if (i >= 1) {
            k_g1<<<dim3(16, 24), 256, 0, stream>>>(rt_cur, rc_cur, 0, inp, arena, W1T, b1, Vif, X2, rc_nxt);
            k_g2<<<dim3(16, 8), 256, 0, stream>>>(rt_cur, rc_cur, 0, inp, arena, X2, Vif, W2T, b2);
        }
        k_select<<<BATCH, 64, 0, stream>>>(i, offi, length, comp, posval, cidx,
                                           ri_cur, ri_nxt, rt_cur, rt_nxt, rc_nxt,
                                           arena, Wq1, bq1, Wq2, bq2, out, (i == 62) ? 1 : 0);
        if (i < 62) offi += (long)BATCH * (63 - i);
    }
    k_out<<<(BATCH * HD + 255) / 256, 256, 0, stream>>>(posval, inp, arena, out);
}

// Round 4
// 11351.985 us; speedup vs baseline: 2.0034x; 2.0034x over previous
//
#include <hip/hip_runtime.h>
#include <math.h>

#define BATCH 512
#define TLEN  64
#define HD    512
#define H2    1024
#define H3    1536
#define HQ    51
#define CHUNK 2048
#define ARENA_BIT 64
#define LDSK 40   // shorts per LDS row: 32 data + 8 pad

typedef __attribute__((ext_vector_type(8))) short bf16x8;
typedef __attribute__((ext_vector_type(16))) float f32x16;

struct Task { int b, el, er, jl, slot; };

__device__ __forceinline__ float sigf(float x) { return 1.0f / (1.0f + expf(-x)); }

__device__ __forceinline__ unsigned short f2bf(float f) {
    unsigned u = __builtin_bit_cast(unsigned, f);
    u += 0x7fffu + ((u >> 16) & 1u);
    return (unsigned short)(u >> 16);
}
__device__ __forceinline__ float bf2f(unsigned short h) {
    unsigned u = ((unsigned)h) << 16;
    return __builtin_bit_cast(float, u);
}
// 3-way bf16 split: f = a + b + c + O(2^-25 * f)
__device__ __forceinline__ void split3(float f, short& a, short& b, short& c) {
    unsigned short h1 = f2bf(f);
    float r1 = f - bf2f(h1);
    unsigned short h2 = f2bf(r1);
    float r2 = r1 - bf2f(h2);
    unsigned short h3 = f2bf(r2);
    a = (short)h1; b = (short)h2; c = (short)h3;
}

__device__ __forceinline__ const float* node_ptr(const float* __restrict__ inp,
                                                 const float* __restrict__ arena,
                                                 int b, int enc)
{
    const float* base = (enc & ARENA_BIT) ? arena : inp;
    return base + ((long)b * TLEN + (enc & (ARENA_BIT - 1))) * HD;
}

// ---------------- prep: weight 3-way splits, posval/cidx/rti/counter init ----------------
__global__ void k_prep(const float* __restrict__ W1, const float* __restrict__ W2,
                       short* __restrict__ W1a, short* __restrict__ W1b, short* __restrict__ W1c,
                       short* __restrict__ W2a, short* __restrict__ W2b, short* __restrict__ W2c,
                       int* __restrict__ posval, int* __restrict__ cidx,
                       int* __restrict__ rti0, int* __restrict__ rti1,
                       int* __restrict__ counters)
{
    long tid = (long)blockIdx.x * blockDim.x + threadIdx.x;
    long nth = (long)gridDim.x * blockDim.x;
    for (long i = tid; i < (long)H3 * H2; i += nth) {
        short a, b, c; split3(W1[i], a, b, c);
        W1a[i] = a; W1b[i] = b; W1c[i] = c;
    }
    for (long i = tid; i < (long)HD * H2; i += nth) {
        short a, b, c; split3(W2[i], a, b, c);
        W2a[i] = a; W2b[i] = b; W2c[i] = c;
    }
    for (long i = tid; i < BATCH * TLEN; i += nth) {
        int j = (int)(i % TLEN);
        posval[i] = j;
        cidx[i] = j;
    }
    for (long i = tid; i < BATCH * 2; i += nth) { rti0[i] = -1; rti1[i] = -1; }
    if (tid < 8) counters[tid] = 0;
}

// ---------------- initial task list ----------------
__global__ void k_init_tasks(const int* __restrict__ length, Task* __restrict__ tasks, int* __restrict__ cnt)
{
    int b = blockIdx.x, j = threadIdx.x;
    int len = length[b];
    if (j < len - 1) {
        int idx = atomicAdd(cnt, 1);
        Task t; t.b = b; t.el = j; t.er = j + 1; t.jl = j; t.slot = j;
        tasks[idx] = t;
    }
}

// ---------------- G1 (MFMA bf16x6): V = [hl,hr]@W1^T + b1 ; r-part -> split X2 ----------------
// tile 64 tasks x 64 cols, K=1024. 4 waves in 2x2 grid, each wave 32x32 via mfma_32x32x16.
__launch_bounds__(256, 3)
__global__ void k_g1(const Task* __restrict__ tasks, const int* __restrict__ cnt, int task_off,
                     const float* __restrict__ inp, const float* __restrict__ arena,
                     const short* __restrict__ W1a, const short* __restrict__ W1b, const short* __restrict__ W1c,
                     const float* __restrict__ bias1,
                     float* __restrict__ Vif,
                     short* __restrict__ X2a, short* __restrict__ X2b, short* __restrict__ X2c,
                     int* zc)
{
    if (zc && blockIdx.x == 0 && blockIdx.y == 0 && threadIdx.x == 0) *zc = 0;
    __shared__ const float* pL[64];
    __shared__ const float* pR[64];
    __shared__ int tok[64];
    __shared__ __align__(16) short sXa[64 * LDSK];
    __shared__ __align__(16) short sXb[64 * LDSK];
    __shared__ __align__(16) short sXc[64 * LDSK];
    int count = *cnt;
    int m_base = task_off + (int)blockIdx.x * 64;
    if (m_base >= count) return;
    int tid = threadIdx.x;
    if (tid < 64) {
        int mg = m_base + tid;
        if (mg < count) {
            Task t = tasks[mg];
            pL[tid] = node_ptr(inp, arena, t.b, t.el);
            pR[tid] = node_ptr(inp, arena, t.b, t.er);
            tok[tid] = 1;
        } else { pL[tid] = inp; pR[tid] = inp; tok[tid] = 0; }
    }
    __syncthreads();
    const int n0 = blockIdx.y * 64;
    const int wid = tid >> 6, lane = tid & 63;
    const int wr = wid >> 1, wc = wid & 1;
    const int lrow = lane & 31, lhi = lane >> 5;
    const int colg = n0 + wc * 32 + lrow;              // 0..1535
    const long wb = (long)colg * H2;
    const int srow = tid >> 2, smk = (tid & 3) * 8;
    const int abase = (wr * 32 + lrow) * LDSK + lhi * 8;

    f32x16 acc;
    #pragma unroll
    for (int r = 0; r < 16; ++r) acc[r] = 0.0f;

    for (int kt = 0; kt < 32; ++kt) {
        const int k0 = kt * 32;
        {
            const float* src = (k0 < HD ? pL[srow] : pR[srow]) + (k0 < HD ? k0 + smk : k0 - HD + smk);
            float4 v0 = *(const float4*)src;
            float4 v1 = *(const float4*)(src + 4);
            float f[8] = {v0.x, v0.y, v0.z, v0.w, v1.x, v1.y, v1.z, v1.w};
            bf16x8 ha, hb, hc;
            #pragma unroll
            for (int j = 0; j < 8; ++j) {
                short s1, s2, s3;
                split3(f[j], s1, s2, s3);
                ha[j] = s1; hb[j] = s2; hc[j] = s3;
            }
            int so = srow * LDSK + smk;
            *(bf16x8*)&sXa[so] = ha;
            *(bf16x8*)&sXb[so] = hb;
            *(bf16x8*)&sXc[so] = hc;
        }
        __syncthreads();
        #pragma unroll
        for (int ch = 0; ch < 2; ++ch) {
            const int ko = k0 + ch * 16 + lhi * 8;
            const int ao = abase + ch * 16;
            bf16x8 a1 = *(const bf16x8*)&sXa[ao];
            bf16x8 a2 = *(const bf16x8*)&sXb[ao];
            bf16x8 a3 = *(const bf16x8*)&sXc[ao];
            bf16x8 b1 = *(const bf16x8*)&W1a[wb + ko];
            bf16x8 b2 = *(const bf16x8*)&W1b[wb + ko];
            bf16x8 b3 = *(const bf16x8*)&W1c[wb + ko];
            acc = __builtin_amdgcn_mfma_f32_32x32x16_bf16(a1, b1, acc, 0, 0, 0);
            acc = __builtin_amdgcn_mfma_f32_32x32x16_bf16(a1, b2, acc, 0, 0, 0);
            acc = __builtin_amdgcn_mfma_f32_32x32x16_bf16(a2, b1, acc, 0, 0, 0);
            acc = __builtin_amdgcn_mfma_f32_32x32x16_bf16(a1, b3, acc, 0, 0, 0);
            acc = __builtin_amdgcn_mfma_f32_32x32x16_bf16(a2, b2, acc, 0, 0, 0);
            acc = __builtin_amdgcn_mfma_f32_32x32x16_bf16(a3, b1, acc, 0, 0, 0);
        }
        __syncthreads();
    }
    #pragma unroll
    for (int r = 0; r < 16; ++r) {
        int rl = wr * 32 + (r & 3) + 8 * (r >> 2) + 4 * lhi;
        if (!tok[rl]) continue;
        int vrow = blockIdx.x * 64 + rl;
        float v = acc[r] + bias1[colg];
        if (n0 < H2) {
            Vif[(long)vrow * H2 + colg] = v;
        } else {
            int c2 = colg - H2;
            float rs = sigf(v);
            float xl = pL[rl][c2] * rs;
            float xr = pR[rl][c2] * rs;
            short s1, s2, s3;
            split3(xl, s1, s2, s3);
            long o1 = (long)vrow * H2 + c2;
            X2a[o1] = s1; X2b[o1] = s2; X2c[o1] = s3;
            split3(xr, s1, s2, s3);
            long o2 = o1 + HD;
            X2a[o2] = s1; X2b[o2] = s2; X2c[o2] = s3;
        }
    }
}

// ---------------- G2 (MFMA bf16x6, no LDS staging): h_hat = X2@W2^T + b2 ; new_h -> arena ----------------
__launch_bounds__(256, 4)
__global__ void k_g2(const Task* __restrict__ tasks, const int* __restrict__ cnt, int task_off,
                     const float* __restrict__ inp, float* __restrict__ arena,
                     const short* __restrict__ X2a, const short* __restrict__ X2b, const short* __restrict__ X2c,
                     const float* __restrict__ Vif,
                     const short* __restrict__ W2a, const short* __restrict__ W2b, const short* __restrict__ W2c,
                     const float* __restrict__ bias2)
{
    __shared__ const float* pL[64];
    __shared__ const float* pR[64];
    __shared__ int dr[64];
    __shared__ int tok[64];
    int count = *cnt;
    int m_base = task_off + (int)blockIdx.x * 64;
    if (m_base >= count) return;
    int tid = threadIdx.x;
    if (tid < 64) {
        int mg = m_base + tid;
        if (mg < count) {
            Task t = tasks[mg];
            pL[tid] = node_ptr(inp, arena, t.b, t.el);
            pR[tid] = node_ptr(inp, arena, t.b, t.er);
            dr[tid] = t.b * TLEN + t.slot;
            tok[tid] = 1;
        } else { pL[tid] = inp; pR[tid] = inp; dr[tid] = 0; tok[tid] = 0; }
    }
    __syncthreads();
    const int n0 = blockIdx.y * 64;
    const int wid = tid >> 6, lane = tid & 63;
    const int wr = wid >> 1, wc = wid & 1;
    const int lrow = lane & 31, lhi = lane >> 5;
    const int colg = n0 + wc * 32 + lrow;              // 0..511
    const long wb = (long)colg * H2;
    const long arow = (long)((int)blockIdx.x * 64 + wr * 32 + lrow) * H2;

    f32x16 acc;
    #pragma unroll
    for (int r = 0; r < 16; ++r) acc[r] = 0.0f;

    for (int kt = 0; kt < 32; ++kt) {
        #pragma unroll
        for (int ch = 0; ch < 2; ++ch) {
            const int ko = kt * 32 + ch * 16 + lhi * 8;
            bf16x8 a1 = *(const bf16x8*)&X2a[arow + ko];
            bf16x8 a2 = *(const bf16x8*)&X2b[arow + ko];
            bf16x8 a3 = *(const bf16x8*)&X2c[arow + ko];
            bf16x8 b1 = *(const bf16x8*)&W2a[wb + ko];
            bf16x8 b2 = *(const bf16x8*)&W2b[wb + ko];
            bf16x8 b3 = *(const bf16x8*)&W2c[wb + ko];
            acc = __builtin_amdgcn_mfma_f32_32x32x16_bf16(a1, b1, acc, 0, 0, 0);
            acc = __builtin_amdgcn_mfma_f32_32x32x16_bf16(a1, b2, acc, 0, 0, 0);
            acc = __builtin_amdgcn_mfma_f32_32x32x16_bf16(a2, b1, acc, 0, 0, 0);
            acc = __builtin_amdgcn_mfma_f32_32x32x16_bf16(a1, b3, acc, 0, 0, 0);
            acc = __builtin_amdgcn_mfma_f32_32x32x16_bf16(a2, b2, acc, 0, 0, 0);
            acc = __builtin_amdgcn_mfma_f32_32x32x16_bf16(a3, b1, acc, 0, 0, 0);
        }
    }
    #pragma unroll
    for (int r = 0; r < 16; ++r) {
        int rl = wr * 32 + (r & 3) + 8 * (r >> 2) + 4 * lhi;
        if (!tok[rl]) continue;
        int vrow = (int)blockIdx.x * 64 + rl;
        float hh = acc[r] + bias2[colg];
        float vi = Vif[(long)vrow * H2 + colg];
        float vf = Vif[(long)vrow * H2 + HD + colg];
        float l = pL[rl][colg];
        float rr = pR[rl][colg];
        float nh = (l + rr) * sigf(vf) + tanhf(hh) * sigf(vi);
        arena[(long)dr[rl] * HD + colg] = nh;
    }
}

// ---------------- G3 (init only): comp score per task from arena (fp64) ----------------
__launch_bounds__(64)
__global__ void k_g3(const Task* __restrict__ tasks, const int* __restrict__ cnt, int task_off,
                     const float* __restrict__ arena,
                     const float* __restrict__ Wq1, const float* __restrict__ bq1,
                     const float* __restrict__ Wq2, const float* __restrict__ bq2,
                     float* __restrict__ comp)
{
    int tgl = task_off + blockIdx.x;
    if (tgl >= *cnt) return;
    Task t = tasks[tgl];
    int tid = threadIdx.x;
    __shared__ float nh[HD];
    __shared__ double part[64];
    const float* src = &arena[((long)t.b * TLEN + t.slot) * HD];
    for (int c = tid; c < HD; c += 64) nh[c] = src[c];
    __syncthreads();
    double p = 0.0;
    if (tid < HQ) {
        const float* wr = &Wq1[(long)tid * HD];
        double s0 = 0.0, s1 = 0.0, s2 = 0.0, s3 = 0.0;
        for (int k = 0; k < HD; k += 4) {
            s0 += (double)wr[k + 0] * (double)nh[k + 0];
            s1 += (double)wr[k + 1] * (double)nh[k + 1];
            s2 += (double)wr[k + 2] * (double)nh[k + 2];
            s3 += (double)wr[k + 3] * (double)nh[k + 3];
        }
        double a = (double)bq1[tid] + s0 + s1 + s2 + s3;
        p = tanh(a) * (double)Wq2[tid];
    }
    part[tid] = p;
    __syncthreads();
    if (tid == 0) {
        double s = 0.0;
        for (int r = 0; r < HQ; ++r) s += part[r];
        s += (double)bq2[0];
        comp[t.b * TLEN + t.jl] = (float)s;
    }
}

// ---------------- select: refresh comp (<=2), argmax, mask, O(1) merge, emit refresh tasks ----------------
__launch_bounds__(64)
__global__ void k_select(int iter, long off_i, const int* __restrict__ length,
                         float* __restrict__ comp, int* __restrict__ posval, int* __restrict__ cidx,
                         const int* __restrict__ rti_cur, int* __restrict__ rti_next,
                         const Task* __restrict__ rtasks_cur, Task* __restrict__ rtasks_next, int* __restrict__ rcnt_next,
                         const float* __restrict__ arena,
                         const float* __restrict__ Wq1, const float* __restrict__ bq1,
                         const float* __restrict__ Wq2, const float* __restrict__ bq2,
                         float* __restrict__ out, int final_flag)
{
    int b = blockIdx.x, tid = threadIdx.x;
    __shared__ float nh[HD];
    __shared__ double part[64];
    __shared__ int sh[4];
    int len = length[b];
    if (final_flag) {
        if (tid == 0 && len == TLEN) posval[b * TLEN + 0] = ARENA_BIT | cidx[b * TLEN + 0];
        return;
    }
    for (int t = 0; t < 2; ++t) {
        int ti = rti_cur[b * 2 + t];
        if (ti < 0) continue;
        Task tk = rtasks_cur[ti];
        const float* src = &arena[((long)b * TLEN + tk.slot) * HD];
        for (int c = tid; c < HD; c += 64) nh[c] = src[c];
        __syncthreads();
        double p = 0.0;
        if (tid < HQ) {
            const float* wr = &Wq1[(long)tid * HD];
            double s0 = 0.0, s1 = 0.0, s2 = 0.0, s3 = 0.0;
            for (int k = 0; k < HD; k += 4) {
                s0 += (double)wr[k + 0] * (double)nh[k + 0];
                s1 += (double)wr[k + 1] * (double)nh[k + 1];
                s2 += (double)wr[k + 2] * (double)nh[k + 2];
                s3 += (double)wr[k + 3] * (double)nh[k + 3];
            }
            double a = (double)bq1[tid] + s0 + s1 + s2 + s3;
            p = tanh(a) * (double)Wq2[tid];
        }
        part[tid] = p;
        __syncthreads();
        if (tid == 0) {
            double s = 0.0;
            for (int r = 0; r < HQ; ++r) s += part[r];
            s += (double)bq2[0];
            comp[b * TLEN + tk.jl] = (float)s;
        }
        __syncthreads();
    }
    int L1 = 63 - iter;
    if (tid == 0) {
        float best = -INFINITY; int bj = 0;
        for (int j = 0; j < L1; ++j) {
            float v = (iter + 1 + j < len) ? comp[b * TLEN + j] : -3.402823466e38f;
            if (v > best) { best = v; bj = j; }
        }
        sh[0] = bj;
    }
    __syncthreads();
    int bj = sh[0];
    for (int j = tid; j < L1; j += 64) out[off_i + (long)b * L1 + j] = (j == bj) ? 1.0f : 0.0f;
    bool active = (iter + 1) < len;
    if (active) {
        int vcnt = len - iter - 2;
        if (tid == 0) {
            sh[1] = cidx[b * TLEN + bj];
            sh[2] = (bj < vcnt) ? cidx[b * TLEN + bj + 1] : -1;
        }
        __syncthreads();
        int sM = sh[1], sOld = sh[2];
        int newL = 63 - iter;
        int pv = 0;  bool dp = (tid >= bj + 1 && tid <= newL - 1);
        if (dp) pv = posval[b * TLEN + tid + 1];
        float cv = 0; int civ = 0; bool dc = (tid >= bj + 1 && tid <= newL - 2);
        if (dc) { cv = comp[b * TLEN + tid + 1]; civ = cidx[b * TLEN + tid + 1]; }
        __syncthreads();
        if (dp) posval[b * TLEN + tid] = pv;
        if (dc) { comp[b * TLEN + tid] = cv; cidx[b * TLEN + tid] = civ; }
        if (tid == 0) posval[b * TLEN + bj] = ARENA_BIT | sM;
        __syncthreads();
        if (tid == 0) {
            for (int t = 0; t < 2; ++t) {
                int jn = bj - 1 + t;
                int r = -1;
                if (jn >= 0 && jn < vcnt) {
                    int slot = (t == 0) ? cidx[b * TLEN + jn] : sOld;
                    cidx[b * TLEN + jn] = slot;
                    r = atomicAdd(rcnt_next, 1);
                    Task tk; tk.b = b;
                    tk.el = posval[b * TLEN + jn];
                    tk.er = posval[b * TLEN + jn + 1];
                    tk.jl = jn; tk.slot = slot;
                    rtasks_next[r] = tk;
                }
                rti_next[b * 2 + t] = r;
            }
        }
    } else {
        if (tid == 0) { rti_next[b * 2] = -1; rti_next[b * 2 + 1] = -1; }
    }
}

// ---------------- final output: root per batch ----------------
__global__ void k_out(const int* __restrict__ posval, const float* __restrict__ inp,
                      const float* __restrict__ arena, float* __restrict__ out)
{
    int i = blockIdx.x * blockDim.x + threadIdx.x;
    if (i < BATCH * HD) {
        int b = i / HD, c = i % HD;
        const float* src = node_ptr(inp, arena, b, posval[b * TLEN + 0]);
        out[i] = src[c];
    }
}

extern "C" void kernel_launch(void* const* d_in, const int* in_sizes, int n_in,
                              void* d_out, int out_size, void* d_ws, size_t ws_size,
                              hipStream_t stream)
{
    const float* inp = (const float*)d_in[0];
    const int* length = (const int*)d_in[1];
    const float* W1 = (const float*)d_in[2];
    const float* b1 = (const float*)d_in[3];
    const float* W2 = (const float*)d_in[4];
    const float* b2 = (const float*)d_in[5];
    const float* Wq1 = (const float*)d_in[6];
    const float* bq1 = (const float*)d_in[7];
    const float* Wq2 = (const float*)d_in[8];
    const float* bq2 = (const float*)d_in[9];
    float* out = (float*)d_out;

    char* p = (char*)d_ws;
    auto alloc = [&](size_t bytes) { char* r = p; p += (bytes + 255) & ~(size_t)255; return r; };
    short* W1a = (short*)alloc((size_t)H3 * H2 * 2);
    short* W1b = (short*)alloc((size_t)H3 * H2 * 2);
    short* W1c = (short*)alloc((size_t)H3 * H2 * 2);
    short* W2a = (short*)alloc((size_t)HD * H2 * 2);
    short* W2b = (short*)alloc((size_t)HD * H2 * 2);
    short* W2c = (short*)alloc((size_t)HD * H2 * 2);
    float* Vif = (float*)alloc((size_t)CHUNK * H2 * 4);
    short* X2a = (short*)alloc((size_t)CHUNK * H2 * 2);
    short* X2b = (short*)alloc((size_t)CHUNK * H2 * 2);
    short* X2c = (short*)alloc((size_t)CHUNK * H2 * 2);
    float* arena = (float*)alloc((size_t)BATCH * TLEN * HD * 4);
    float* comp = (float*)alloc((size_t)BATCH * TLEN * 4);
    int* posval = (int*)alloc((size_t)BATCH * TLEN * 4);
    int* cidx = (int*)alloc((size_t)BATCH * TLEN * 4);
    Task* itasks = (Task*)alloc((size_t)BATCH * (TLEN - 1) * sizeof(Task));
    Task* rtasks0 = (Task*)alloc((size_t)2 * BATCH * sizeof(Task));
    Task* rtasks1 = (Task*)alloc((size_t)2 * BATCH * sizeof(Task));
    int* rti0 = (int*)alloc(BATCH * 2 * 4);
    int* rti1 = (int*)alloc(BATCH * 2 * 4);
    int* counters = (int*)alloc(256);
    int* cnt_init = counters + 0;
    int* rcnt0 = counters + 1;
    int* rcnt1 = counters + 2;

    k_prep<<<2048, 256, 0, stream>>>(W1, W2, W1a, W1b, W1c, W2a, W2b, W2c,
                                     posval, cidx, rti0, rti1, counters);
    k_init_tasks<<<BATCH, 64, 0, stream>>>(length, itasks, cnt_init);
    for (int c = 0; c < 16; ++c) {
        k_g1<<<dim3(CHUNK / 64, 24), 256, 0, stream>>>(itasks, cnt_init, c * CHUNK, inp, arena,
                                                       W1a, W1b, W1c, b1, Vif, X2a, X2b, X2c, nullptr);
        k_g2<<<dim3(CHUNK / 64, 8), 256, 0, stream>>>(itasks, cnt_init, c * CHUNK, inp, arena,
                                                      X2a, X2b, X2c, Vif, W2a, W2b, W2c, b2);
        k_g3<<<CHUNK, 64, 0, stream>>>(itasks, cnt_init, c * CHUNK, arena, Wq1, bq1, Wq2, bq2, comp);
    }
    long offi = (long)BATCH * HD;
    for (int i = 0; i < 63; ++i) {
        int par = i & 1;
        Task* rt_cur = par ? rtasks1 : rtasks0;
        Task* rt_nxt = par ? rtasks0 : rtasks1;
        int* rc_cur = par ? rcnt1 : rcnt0;
        int* rc_nxt = par ? rcnt0 : rcnt1;
        int* ri_cur = par ? rti1 : rti0;
        int* ri_nxt = par ? rti0 : rti1;
        if (i >= 1) {
            k_g1<<<dim3(16, 24), 256, 0, stream>>>(rt_cur, rc_cur, 0, inp, arena,
                                                   W1a, W1b, W1c, b1, Vif, X2a, X2b, X2c, rc_nxt);
            k_g2<<<dim3(16, 8), 256, 0, stream>>>(rt_cur, rc_cur, 0, inp, arena,
                                                  X2a, X2b, X2c, Vif, W2a, W2b, W2c, b2);
        }
        k_select<<<BATCH, 64, 0, stream>>>(i, offi, length, comp, posval, cidx,
                                           ri_cur, ri_nxt, rt_cur, rt_nxt, rc_nxt,
                                           arena, Wq1, bq1, Wq2, bq2, out, (i == 62) ? 1 : 0);
        if (i < 62) offi += (long)BATCH * (63 - i);
    }
    k_out<<<(BATCH * HD + 255) / 256, 256, 0, stream>>>(posval, inp, arena, out);
}